// Round 10
// baseline (419.558 us; speedup 1.0000x reference)
//
#include <hip/hip_runtime.h>

typedef _Float16 f16;
typedef _Float16 f16x2 __attribute__((ext_vector_type(2)));
typedef _Float16 f16x4 __attribute__((ext_vector_type(4)));
typedef _Float16 f16x8 __attribute__((ext_vector_type(8)));
typedef float f32x4 __attribute__((ext_vector_type(4)));

#define LOG2E_X2 2.8853900817779268f

// Fourier coefficients: d_m = (2*pi/10)/sinh(pi^2*m/10); tanh(s) ~= 0.2*s + sum d_m sin(0.628319*m*s)
__constant__ float D8[8] = {0.543915f, 0.177997f, 0.0652351f, 0.0242575f,
                            0.00903807f, 0.00336823f, 0.00125536f, 0.000467884f};

static __device__ __forceinline__ void gl2lds16(const void* g, void* l) {
  __builtin_amdgcn_global_load_lds((const __attribute__((address_space(1))) void*)g,
                                   (__attribute__((address_space(3))) void*)l, 16, 0, 0);
}

// ================= new pipeline =================

// X f32 [8,1024,512] -> Xh f16 (same layout) + XhT f16 [8,512,1024]
__global__ __launch_bounds__(256) void k_prep_x(const float* __restrict__ X,
                                                f16* __restrict__ Xh, f16* __restrict__ XhT) {
  const int ht = blockIdx.x, it = blockIdx.y, b = blockIdx.z;
  __shared__ f16 Lt[64][72];
  const int t = threadIdx.x;
  const int r = t >> 4, c4 = (t & 15) * 4;
  const float* Xb = X + ((size_t)b * 1024 + it * 64) * 512 + ht * 64;
#pragma unroll
  for (int k = 0; k < 4; ++k) {
    const int rr = r + 16 * k;
    float4 v = *(const float4*)&Xb[(size_t)rr * 512 + c4];
    f16 h0 = (f16)v.x, h1 = (f16)v.y, h2 = (f16)v.z, h3 = (f16)v.w;
    *(f16x4*)&Xh[((size_t)b * 1024 + it * 64 + rr) * 512 + ht * 64 + c4] = {h0, h1, h2, h3};
    Lt[c4 + 0][rr] = h0; Lt[c4 + 1][rr] = h1; Lt[c4 + 2][rr] = h2; Lt[c4 + 3][rr] = h3;
  }
  __syncthreads();
  const int hr = t >> 2, seg = t & 3;
  f16* dst = &XhT[((size_t)b * 512 + ht * 64 + hr) * 1024 + it * 64 + seg * 16];
  *(f16x8*)(dst) = *(const f16x8*)&Lt[hr][seg * 16];
  *(f16x8*)(dst + 8) = *(const f16x8*)&Lt[hr][seg * 16 + 8];
}

// Wh = concat(W1,W2) as f16 [1024][512]
__global__ __launch_bounds__(256) void k_prep_w(const float* __restrict__ W1,
                                                const float* __restrict__ W2,
                                                f16* __restrict__ Wh) {
  const int row = blockIdx.x, z = blockIdx.y, t = threadIdx.x;
  const float* W = z ? W2 : W1;
  float2 v = *(const float2*)&W[(size_t)row * 512 + t * 2];
  *(f16x2*)&Wh[(size_t)z * 262144 + (size_t)row * 512 + t * 2] = {(f16)v.x, (f16)v.y};
}

__global__ void k_prep_b(const float* __restrict__ b1, const float* __restrict__ b2,
                         float* __restrict__ biasCat) {
  const int t = blockIdx.x * 256 + threadIdx.x;  // 1024 total
  biasCat[t] = t < 512 ? b1[t] : b2[t - 512];
}

// trig factor build; u is [8192][1024] f32, row i holds u1[i][0:512] | u2[i][512:1024]
template <int NM>
__global__ __launch_bounds__(256) void k_trig(const float* __restrict__ u,
                                              const float* __restrict__ q,
                                              f16* __restrict__ At, f16* __restrict__ Bt,
                                              float* __restrict__ qa, float* __restrict__ qb,
                                              int m0, int wq) {
  const int i = blockIdx.x, t = threadIdx.x;
  const float w = 0.62831853f;
  const float2 a2 = *(const float2*)&u[(size_t)i * 1024 + 2 * t];
  const float2 b2 = *(const float2*)&u[(size_t)i * 1024 + 512 + 2 * t];
  const float2 q2 = *(const float2*)&q[2 * t];
  if (wq) {
    float sa = q2.x * a2.x + q2.y * a2.y;
    float sb = q2.x * b2.x + q2.y * b2.y;
#pragma unroll
    for (int o = 1; o < 64; o <<= 1) { sa += __shfl_xor(sa, o); sb += __shfl_xor(sb, o); }
    __shared__ float red[8];
    const int lane = t & 63, widx = t >> 6;
    if (lane == 0) { red[widx] = sa; red[4 + widx] = sb; }
    __syncthreads();
    if (t == 0) qa[i] = red[0] + red[1] + red[2] + red[3];
    if (t == 1) qb[i] = red[4] + red[5] + red[6] + red[7];
  }
  float s1[4], c1[4], sm_[4], cm_[4];
  const float ang[4] = {w * a2.x, w * a2.y, w * b2.x, w * b2.y};
#pragma unroll
  for (int uu = 0; uu < 4; ++uu) {
    __sincosf(ang[uu], &s1[uu], &c1[uu]);
    if (m0 == 1) { sm_[uu] = s1[uu]; cm_[uu] = c1[uu]; }
    else __sincosf(m0 * ang[uu], &sm_[uu], &cm_[uu]);
  }
  const size_t ldT = (size_t)NM * 1024;
  f16* Ar = At + (size_t)i * ldT + 2 * t;
  f16* Br = Bt + (size_t)i * ldT + 2 * t;
#pragma unroll
  for (int j = 0; j < NM; ++j) {
    const float dm = D8[m0 - 1 + j];
    const float qdx = q2.x * dm, qdy = q2.y * dm;
    *(f16x2*)(Ar + j * 1024)       = {(f16)(qdx * sm_[0]), (f16)(qdy * sm_[1])};
    *(f16x2*)(Ar + j * 1024 + 512) = {(f16)(qdx * cm_[0]), (f16)(qdy * cm_[1])};
    *(f16x2*)(Br + j * 1024)       = {(f16)cm_[2], (f16)cm_[3]};
    *(f16x2*)(Br + j * 1024 + 512) = {(f16)sm_[2], (f16)sm_[3]};
    if (j + 1 < NM) {
#pragma unroll
      for (int uu = 0; uu < 4; ++uu) {
        const float ns = sm_[uu] * c1[uu] + cm_[uu] * s1[uu];
        const float nc = cm_[uu] * c1[uu] - sm_[uu] * s1[uu];
        sm_[uu] = ns; cm_[uu] = nc;
      }
    }
  }
}

// ---------- scores GEMM: 128x128 tile, BK=32, 256 thr, 32KB LDS -> 4 blocks/CU ----------
// Frozen r3 2-barrier schedule (stage-at-top, __syncthreads drain). K halved by z>>3
// into P0/P1 (z&7 = batch). Bank swizzle for 64B rows: phys_slot = k_slot ^ ((r^(r>>2))&3)
// -> exactly 2 lanes per 4-bank group (2-way = free). Applied to global source (linear
// gl2lds dest) and to the ds_read address (rule #21 both-sides involution).
template <int ACC>
__global__ __launch_bounds__(256, 4) void k_gemm32(
    const f16* __restrict__ A, const f16* __restrict__ B, float* __restrict__ C,
    int Kloop, int ldAB, long halfA, long halfC) {
  __shared__ alignas(16) char smA[2][8192];
  __shared__ alignas(16) char smB[2][8192];
  const int t = threadIdx.x;
  const int nx = blockIdx.x, my = blockIdx.y, z = blockIdx.z;
  const int b = z & 7, h = z >> 3;
  const f16* Ab = A + ((size_t)(b * 1024 + my * 128)) * ldAB + h * halfA;
  const f16* Bb = B + ((size_t)(b * 1024 + nx * 128)) * ldAB + h * halfA;
  float* Cb = C + h * halfC + ((size_t)(b * 1024 + my * 128)) * 1024 + nx * 128;
  const int wid = t >> 6, lane = t & 63;
  const int wr = wid >> 1, wc = wid & 1;
  const int rl = lane & 15, kc = lane >> 4;
  f32x4 acc[4][4] = {};

  auto stage = [&](int buf, int kt) {
    const f16* gA = Ab + kt * 32;
    const f16* gB = Bb + kt * 32;
#pragma unroll
    for (int ii = 0; ii < 2; ++ii) {
      const int idx = ii * 256 + t;
      const int row = idx >> 2, sp = idx & 3;
      const int sl = sp ^ ((row ^ (row >> 2)) & 3);   // logical k-slot fetched
      gl2lds16(gA + (size_t)row * ldAB + sl * 8, smA[buf] + ii * 4096 + wid * 1024);
      gl2lds16(gB + (size_t)row * ldAB + sl * 8, smB[buf] + ii * 4096 + wid * 1024);
    }
  };

  const int nkt = Kloop >> 5;
  stage(0, 0);
  __syncthreads();
  for (int kt = 0; kt < nkt; ++kt) {
    const int cur = kt & 1;
    if (kt + 1 < nkt) stage(cur ^ 1, kt + 1);
    const char* lA = smA[cur];
    const char* lB = smB[cur];
    f16x8 av[4], bv[4];
#pragma unroll
    for (int fi = 0; fi < 4; ++fi) {
      const int r = wr * 64 + fi * 16 + rl;
      av[fi] = *(const f16x8*)(lA + r * 64 + ((kc ^ ((r ^ (r >> 2)) & 3)) << 4));
    }
#pragma unroll
    for (int fj = 0; fj < 4; ++fj) {
      const int c = wc * 64 + fj * 16 + rl;
      bv[fj] = *(const f16x8*)(lB + c * 64 + ((kc ^ ((c ^ (c >> 2)) & 3)) << 4));
    }
#pragma unroll
    for (int fi = 0; fi < 4; ++fi)
#pragma unroll
      for (int fj = 0; fj < 4; ++fj)
        acc[fi][fj] = __builtin_amdgcn_mfma_f32_16x16x32_f16(av[fi], bv[fj], acc[fi][fj], 0, 0, 0);
    __syncthreads();
  }

#pragma unroll
  for (int fj = 0; fj < 4; ++fj) {
    const int gcol = wc * 64 + fj * 16 + rl;
#pragma unroll
    for (int fi = 0; fi < 4; ++fi) {
      const int grow0 = wr * 64 + fi * 16 + kc * 4;
      f32x4 v = acc[fi][fj];
#pragma unroll
      for (int r = 0; r < 4; ++r) {
        const size_t o = (size_t)(grow0 + r) * 1024 + gcol;
        float x = v[r];
        if (ACC) x += Cb[o];
        Cb[o] = x;
      }
    }
  }
}

// ---------- generic f16 NT GEMM, round-3 schedule (frozen), tile-parameterized ----------
// MODE 0: u = Xh @ WhCat^T + biasCat        (C f32 [8192][1024])
// MODE 2: h = a16 @ XhT^T per batch         (C f32 [8,1024,512])
template <int MODE, int ACC, int T, int WR, int WC, int FI, int FJ>
__global__ __launch_bounds__(T, 2) void k_gemmG(
    const f16* __restrict__ A, const f16* __restrict__ B, float* __restrict__ C,
    const float* __restrict__ bias0, int Kloop, int ldAB, long halfA, long halfC) {
  constexpr int BM = WR * FI * 16;
  constexpr int BN = WC * FJ * 16;
  __shared__ alignas(16) char smA[2][BM * 128];
  __shared__ alignas(16) char smB[2][BN * 128];
  const int t = threadIdx.x;
  const int nx = blockIdx.x, my = blockIdx.y, z = blockIdx.z;
  const f16* Ab; const f16* Bb; float* Cb; const float* bias = nullptr;
  int ldC;
  if (MODE == 0) {
    Ab = A + (size_t)my * BM * ldAB;
    Bb = B + (size_t)nx * BN * ldAB;
    Cb = C + (size_t)my * BM * 1024 + nx * BN;
    bias = bias0 + nx * BN;
    ldC = 1024;
  } else {
    Ab = A + (size_t)z * 1048576 + (size_t)my * BM * ldAB;
    Bb = B + (size_t)z * 524288 + (size_t)nx * BN * ldAB;
    Cb = C + (size_t)z * 524288 + (size_t)my * BM * 512 + nx * BN;
    ldC = 512;
  }
  const int wid = t >> 6, lane = t & 63;
  const int wr = wid / WC, wc = wid % WC;
  const int rl = lane & 15, kc = lane >> 4;
  f32x4 acc[FI][FJ] = {};

  auto stage = [&](int buf, int kt) {
    const f16* gA = Ab + kt * 64;
    const f16* gB = Bb + kt * 64;
    constexpr int LA = BM * 8 / T, LB = BN * 8 / T;
#pragma unroll
    for (int ii = 0; ii < LA; ++ii) {
      const int idx = ii * T + t;
      const int row = idx >> 3, c = idx & 7;
      gl2lds16(gA + (size_t)row * ldAB + ((c ^ (row & 7)) * 8),
               smA[buf] + ii * (T * 16) + wid * 1024);
    }
#pragma unroll
    for (int ii = 0; ii < LB; ++ii) {
      const int idx = ii * T + t;
      const int row = idx >> 3, c = idx & 7;
      gl2lds16(gB + (size_t)row * ldAB + ((c ^ (row & 7)) * 8),
               smB[buf] + ii * (T * 16) + wid * 1024);
    }
  };

  const int nkt = Kloop >> 6;
  stage(0, 0);
  __syncthreads();
  for (int kt = 0; kt < nkt; ++kt) {
    const int cur = kt & 1;
    if (kt + 1 < nkt) stage(cur ^ 1, kt + 1);
    const char* lA = smA[cur];
    const char* lB = smB[cur];
#pragma unroll
    for (int kk = 0; kk < 2; ++kk) {
      f16x8 av[FI], bv[FJ];
#pragma unroll
      for (int fi = 0; fi < FI; ++fi) {
        const int rloc = (wr * FI + fi) * 16 + rl;
        av[fi] = *(const f16x8*)(lA + rloc * 128 + (((kc + 4 * kk) ^ (rloc & 7)) << 4));
      }
#pragma unroll
      for (int fj = 0; fj < FJ; ++fj) {
        const int cloc = (wc * FJ + fj) * 16 + rl;
        bv[fj] = *(const f16x8*)(lB + cloc * 128 + (((kc + 4 * kk) ^ (cloc & 7)) << 4));
      }
#pragma unroll
      for (int fi = 0; fi < FI; ++fi)
#pragma unroll
        for (int fj = 0; fj < FJ; ++fj)
          acc[fi][fj] = __builtin_amdgcn_mfma_f32_16x16x32_f16(av[fi], bv[fj], acc[fi][fj], 0, 0, 0);
    }
    __syncthreads();
  }

#pragma unroll
  for (int fj = 0; fj < FJ; ++fj) {
    const int gcol = (wc * FJ + fj) * 16 + rl;
    const float bvv = (MODE == 0) ? bias[gcol] : 0.f;
#pragma unroll
    for (int fi = 0; fi < FI; ++fi) {
      const int grow0 = (wr * FI + fi) * 16 + kc * 4;
      f32x4 v = acc[fi][fj];
#pragma unroll
      for (int r = 0; r < 4; ++r) {
        const size_t o = (size_t)(grow0 + r) * ldC + gcol;
        float x = v[r] + bvv;
        if (ACC) x += Cb[o];
        Cb[o] = x;
      }
    }
  }
}

// softmax over j of u = P0+P1+0.2*(qa_i+qb_j); writes a (f32) and a16 (f16)
__global__ __launch_bounds__(256) void k_softmax2(const float* __restrict__ P0,
                                                  const float* __restrict__ P1,
                                                  const float* __restrict__ qa,
                                                  const float* __restrict__ qb,
                                                  float* __restrict__ out_a,
                                                  f16* __restrict__ a16) {
  const int row = blockIdx.x, t = threadIdx.x;
  const int b = row >> 10;
  const size_t off = (size_t)row * 1024 + t * 4;
  float4 p0 = *(const float4*)(P0 + off);
  float4 p1 = *(const float4*)(P1 + off);
  float4 qb4 = *(const float4*)(qb + (size_t)b * 1024 + t * 4);
  const float qi = qa[row];
  float4 v;
  v.x = p0.x + p1.x + 0.2f * (qi + qb4.x);
  v.y = p0.y + p1.y + 0.2f * (qi + qb4.y);
  v.z = p0.z + p1.z + 0.2f * (qi + qb4.z);
  v.w = p0.w + p1.w + 0.2f * (qi + qb4.w);
  float m = fmaxf(fmaxf(v.x, v.y), fmaxf(v.z, v.w));
#pragma unroll
  for (int o = 1; o < 64; o <<= 1) m = fmaxf(m, __shfl_xor(m, o));
  __shared__ float red[4];
  const int w = t >> 6, ln = t & 63;
  if (ln == 0) red[w] = m;
  __syncthreads();
  m = fmaxf(fmaxf(red[0], red[1]), fmaxf(red[2], red[3]));
  v.x = __expf(v.x - m); v.y = __expf(v.y - m);
  v.z = __expf(v.z - m); v.w = __expf(v.w - m);
  float s = v.x + v.y + v.z + v.w;
#pragma unroll
  for (int o = 1; o < 64; o <<= 1) s += __shfl_xor(s, o);
  __syncthreads();
  if (ln == 0) red[w] = s;
  __syncthreads();
  s = red[0] + red[1] + red[2] + red[3];
  const float inv = 1.0f / s;
  v.x *= inv; v.y *= inv; v.z *= inv; v.w *= inv;
  *(float4*)(out_a + off) = v;
  *(f16x4*)(a16 + off) = {(f16)v.x, (f16)v.y, (f16)v.z, (f16)v.w};
}

// ================= old (fallback) pipeline =================
typedef short s16x2 __attribute__((ext_vector_type(2)));

static __device__ __forceinline__ float fdot2f(f16x2 a, f16x2 b, float c) {
#if __has_builtin(__builtin_amdgcn_fdot2)
  return __builtin_amdgcn_fdot2(a, b, c, false);
#else
  return c + (float)a[0] * (float)b[0] + (float)a[1] * (float)b[1];
#endif
}

__global__ void k_qprep(const float* __restrict__ q, f16* __restrict__ qh,
                        float* __restrict__ qsum) {
  const int t = threadIdx.x;
  float v = q[t];
  qh[t] = (f16)v;
  float s = v;
#pragma unroll
  for (int o = 1; o < 64; o <<= 1) s += __shfl_xor(s, o);
  __shared__ float red[8];
  if ((t & 63) == 0) red[t >> 6] = s;
  __syncthreads();
  if (t == 0) {
    float tot = 0.f;
#pragma unroll
    for (int i = 0; i < 8; ++i) tot += red[i];
    *qsum = tot;
  }
}

__global__ __launch_bounds__(256) void k_gemm_exp(
    const float* __restrict__ X, const float* __restrict__ W1,
    const float* __restrict__ b1, const float* __restrict__ W2,
    const float* __restrict__ b2, f16* __restrict__ e1, f16* __restrict__ e2) {
  const int z = blockIdx.z;
  const float* W = z ? W2 : W1;
  const float* bias = z ? b2 : b1;
  f16* out = z ? e2 : e1;
  const int r0 = blockIdx.y * 64;
  const int c0 = blockIdx.x * 64;
  __shared__ alignas(16) float Xs[64][68];
  __shared__ alignas(16) float Ws[64][68];
  const int t = threadIdx.x;
  const int row = t >> 2, seg = t & 3;
  const int tr = t >> 4, tc = t & 15;
  float acc[4][4] = {};
#pragma unroll 1
  for (int k0 = 0; k0 < 512; k0 += 64) {
    const float4* gx = (const float4*)(X + (size_t)(r0 + row) * 512 + k0 + seg * 16);
    float4* lx = (float4*)(&Xs[row][seg * 16]);
    lx[0] = gx[0]; lx[1] = gx[1]; lx[2] = gx[2]; lx[3] = gx[3];
    const float4* gw = (const float4*)(W + (size_t)(c0 + row) * 512 + k0 + seg * 16);
    float4* lw = (float4*)(&Ws[row][seg * 16]);
    lw[0] = gw[0]; lw[1] = gw[1]; lw[2] = gw[2]; lw[3] = gw[3];
    __syncthreads();
#pragma unroll 4
    for (int kk = 0; kk < 64; kk += 4) {
      float4 av[4], bv[4];
#pragma unroll
      for (int ii = 0; ii < 4; ++ii) av[ii] = *(const float4*)&Xs[tr + 16 * ii][kk];
#pragma unroll
      for (int jj = 0; jj < 4; ++jj) bv[jj] = *(const float4*)&Ws[tc + 16 * jj][kk];
#pragma unroll
      for (int ii = 0; ii < 4; ++ii) {
#pragma unroll
        for (int jj = 0; jj < 4; ++jj) {
          acc[ii][jj] = fmaf(av[ii].x, bv[jj].x, acc[ii][jj]);
          acc[ii][jj] = fmaf(av[ii].y, bv[jj].y, acc[ii][jj]);
          acc[ii][jj] = fmaf(av[ii].z, bv[jj].z, acc[ii][jj]);
          acc[ii][jj] = fmaf(av[ii].w, bv[jj].w, acc[ii][jj]);
        }
      }
    }
    __syncthreads();
  }
#pragma unroll
  for (int ii = 0; ii < 4; ++ii) {
    const int r = r0 + tr + 16 * ii;
#pragma unroll
    for (int jj = 0; jj < 4; ++jj) {
      const int c = c0 + tc + 16 * jj;
      float u = acc[ii][jj] + bias[c];
      float val = u * LOG2E_X2 - 4.0f;
      val = fminf(6.6759f, fmaxf(-14.6759f, val));
      out[(size_t)r * 512 + c] = (f16)exp2f(val);
    }
  }
}

template <int P>
static __device__ __forceinline__ void tanh_dot_step(const f16x8 (&Av)[4],
                                                     const f16x8 (&Bv)[4],
                                                     const f16x8& Qv, float (&acc)[4][4],
                                                     int c256, int kmag, int two2) {
  f16x2 qp = __builtin_shufflevector(Qv, Qv, 2 * P, 2 * P + 1);
#pragma unroll
  for (int jj = 0; jj < 4; ++jj) {
    f16x2 bp = __builtin_shufflevector(Bv[jj], Bv[jj], 2 * P, 2 * P + 1);
#pragma unroll
    for (int ii = 0; ii < 4; ++ii) {
      f16x2 ap = __builtin_shufflevector(Av[ii], Av[ii], 2 * P, 2 * P + 1);
      f16x2 d, r, tt;
      asm("v_pk_fma_f16 %0, %3, %4, %5\n\t"
          "v_pk_sub_i16 %1, %6, %0\n\t"
          "v_pk_fma_f16 %2, %0, %1, %7 neg_lo:[1,0,0] neg_hi:[1,0,0]\n\t"
          "v_pk_mul_f16 %1, %1, %2\n\t"
          "v_pk_fma_f16 %2, %0, %1, %7 neg_lo:[1,0,0] neg_hi:[1,0,0]\n\t"
          "v_pk_mul_f16 %1, %1, %2"
          : "=&v"(d), "=&v"(r), "=&v"(tt)
          : "v"(ap), "v"(bp), "v"(c256), "v"(kmag), "v"(two2));
      acc[ii][jj] = fdot2f(r, qp, acc[ii][jj]);
    }
  }
}

__global__ __launch_bounds__(256) void k_scores(const f16* __restrict__ e1,
                                                const f16* __restrict__ e2,
                                                const f16* __restrict__ qh,
                                                const float* __restrict__ qsum_p,
                                                float* __restrict__ out_a) {
  const int b = blockIdx.z, it = blockIdx.y, jt = blockIdx.x;
  __shared__ alignas(16) f16 As[64][72];
  __shared__ alignas(16) f16 Bs[64][72];
  __shared__ alignas(16) f16 Qs[512];
  const int t = threadIdx.x;
  const size_t eA = (size_t)(b * 1024 + it * 64) * 512;
  const size_t eB = (size_t)(b * 1024 + jt * 64) * 512;
  if (t < 64) ((uint4*)Qs)[t] = ((const uint4*)qh)[t];
  const int row = t >> 2, seg = t & 3;
  const int tr = t >> 4, tc = t & 15;
  const int c256 = 0x1C001C00;
  const int kmag = 0x77987798;
  const int two2 = 0x40004000;
  float acc[4][4] = {};
#pragma unroll 1
  for (int h0 = 0; h0 < 512; h0 += 64) {
    const f16* gA = e1 + eA + (size_t)row * 512 + h0;
    const f16* gB = e2 + eB + (size_t)row * 512 + h0;
    *(uint4*)(&As[row][seg * 8]) = *(const uint4*)(gA + seg * 8);
    *(uint4*)(&As[row][seg * 8 + 32]) = *(const uint4*)(gA + seg * 8 + 32);
    *(uint4*)(&Bs[row][seg * 8]) = *(const uint4*)(gB + seg * 8);
    *(uint4*)(&Bs[row][seg * 8 + 32]) = *(const uint4*)(gB + seg * 8 + 32);
    __syncthreads();
#pragma unroll 2
    for (int g = 0; g < 8; ++g) {
      f16x8 Av[4], Bv[4], Qv;
#pragma unroll
      for (int ii = 0; ii < 4; ++ii) Av[ii] = *(const f16x8*)&As[tr + 16 * ii][g * 8];
#pragma unroll
      for (int jj = 0; jj < 4; ++jj) Bv[jj] = *(const f16x8*)&Bs[tc + 16 * jj][g * 8];
      Qv = *(const f16x8*)&Qs[h0 + g * 8];
      tanh_dot_step<0>(Av, Bv, Qv, acc, c256, kmag, two2);
      tanh_dot_step<1>(Av, Bv, Qv, acc, c256, kmag, two2);
      tanh_dot_step<2>(Av, Bv, Qv, acc, c256, kmag, two2);
      tanh_dot_step<3>(Av, Bv, Qv, acc, c256, kmag, two2);
    }
    __syncthreads();
  }
  const float qs = *qsum_p;
#pragma unroll
  for (int ii = 0; ii < 4; ++ii) {
    const size_t orow = (size_t)(b * 1024 + it * 64 + tr + 16 * ii) * 1024;
#pragma unroll
    for (int jj = 0; jj < 4; ++jj)
      out_a[orow + jt * 64 + tc + 16 * jj] = qs - acc[ii][jj] * (1.0f / 128.0f);
  }
}

__global__ __launch_bounds__(256) void k_softmax(float* __restrict__ a) {
  float* row = a + (size_t)blockIdx.x * 1024;
  const int t = threadIdx.x;
  float4 v = ((const float4*)row)[t];
  float m = fmaxf(fmaxf(v.x, v.y), fmaxf(v.z, v.w));
#pragma unroll
  for (int o = 1; o < 64; o <<= 1) m = fmaxf(m, __shfl_xor(m, o));
  __shared__ float red[4];
  const int w = t >> 6, ln = t & 63;
  if (ln == 0) red[w] = m;
  __syncthreads();
  m = fmaxf(fmaxf(red[0], red[1]), fmaxf(red[2], red[3]));
  v.x = __expf(v.x - m); v.y = __expf(v.y - m);
  v.z = __expf(v.z - m); v.w = __expf(v.w - m);
  float s = v.x + v.y + v.z + v.w;
#pragma unroll
  for (int o = 1; o < 64; o <<= 1) s += __shfl_xor(s, o);
  __syncthreads();
  if (ln == 0) red[w] = s;
  __syncthreads();
  s = red[0] + red[1] + red[2] + red[3];
  const float inv = 1.0f / s;
  v.x *= inv; v.y *= inv; v.z *= inv; v.w *= inv;
  ((float4*)row)[t] = v;
}

__global__ __launch_bounds__(256) void k_av(const float* __restrict__ a,
                                            const float* __restrict__ X,
                                            float* __restrict__ h) {
  const int b = blockIdx.z;
  const int i0 = blockIdx.y * 64;
  const int c0 = blockIdx.x * 64;
  __shared__ alignas(16) float As[64][68];
  __shared__ alignas(16) float Xs[64][68];
  const float* Ab = a + (size_t)b * 1024 * 1024;
  const float* Xb = X + (size_t)b * 1024 * 512;
  const int t = threadIdx.x;
  const int row = t >> 2, seg = t & 3;
  const int tr = t >> 4, tc = t & 15;
  float acc[4][4] = {};
#pragma unroll 1
  for (int k0 = 0; k0 < 1024; k0 += 64) {
    const float4* ga = (const float4*)(Ab + (size_t)(i0 + row) * 1024 + k0 + seg * 16);
    float4* la = (float4*)(&As[row][seg * 16]);
    la[0] = ga[0]; la[1] = ga[1]; la[2] = ga[2]; la[3] = ga[3];
    const float4* gx = (const float4*)(Xb + (size_t)(k0 + row) * 512 + c0 + seg * 16);
    float4* lx = (float4*)(&Xs[row][seg * 16]);
    lx[0] = gx[0]; lx[1] = gx[1]; lx[2] = gx[2]; lx[3] = gx[3];
    __syncthreads();
#pragma unroll 8
    for (int k = 0; k < 64; ++k) {
      float av[4], bv[4];
#pragma unroll
      for (int ii = 0; ii < 4; ++ii) av[ii] = As[tr + 16 * ii][k];
#pragma unroll
      for (int jj = 0; jj < 4; ++jj) bv[jj] = Xs[k][tc + 16 * jj];
#pragma unroll
      for (int ii = 0; ii < 4; ++ii) {
#pragma unroll
        for (int jj = 0; jj < 4; ++jj)
          acc[ii][jj] = fmaf(av[ii], bv[jj], acc[ii][jj]);
      }
    }
    __syncthreads();
  }
#pragma unroll
  for (int ii = 0; ii < 4; ++ii) {
    const size_t orow = (size_t)b * 1024 * 512 + (size_t)(i0 + tr + 16 * ii) * 512;
#pragma unroll
    for (int jj = 0; jj < 4; ++jj)
      h[orow + c0 + tc + 16 * jj] = acc[ii][jj];
  }
}

// ================= host =================
extern "C" void kernel_launch(void* const* d_in, const int* in_sizes, int n_in,
                              void* d_out, int out_size, void* d_ws, size_t ws_size,
                              hipStream_t stream) {
  const float* inputs = (const float*)d_in[0];
  const float* W1 = (const float*)d_in[1];
  const float* b1 = (const float*)d_in[2];
  const float* W2 = (const float*)d_in[3];
  const float* b2 = (const float*)d_in[4];
  const float* q = (const float*)d_in[5];

  float* out_h = (float*)d_out;            // [8,1024,512]
  float* out_a = out_h + 4194304;          // [8,1024,1024]

  const size_t FIXED = 101781504ULL;       // Xh+XhT+Wh+a16+qa+qb+biasCat+P0+P1
  const size_t PER_M = 33554432ULL;        // At+Bt trig per m
  if (ws_size < FIXED + PER_M) {
    // fallback: verified elementwise pipeline (needs only ~17 MB)
    char* ws = (char*)d_ws;
    f16* e1 = (f16*)ws;
    f16* e2 = (f16*)(ws + 8388608);
    f16* qh = (f16*)(ws + 16777216);
    float* qsum = (float*)(ws + 16778240);
    k_qprep<<<1, 512, 0, stream>>>(q, qh, qsum);
    k_gemm_exp<<<dim3(8, 128, 2), 256, 0, stream>>>(inputs, W1, b1, W2, b2, e1, e2);
    k_scores<<<dim3(16, 16, 8), 256, 0, stream>>>(e1, e2, qh, qsum, out_a);
    k_softmax<<<8192, 256, 0, stream>>>(out_a);
    k_av<<<dim3(8, 16, 8), 256, 0, stream>>>(out_a, inputs, out_h);
    return;
  }

  int nm = 8;
  while (FIXED + (size_t)nm * PER_M > ws_size) nm >>= 1;

  char* p = (char*)d_ws;
  f16* Xh = (f16*)p;            p += 8388608;
  f16* XhT = (f16*)p;           p += 8388608;
  f16* Wh = (f16*)p;            p += 1048576;
  f16* a16 = (f16*)p;           p += 16777216;
  float* qa = (float*)p;        p += 32768;
  float* qb = (float*)p;        p += 32768;
  float* biasCat = (float*)p;   p += 4096;
  float* P0 = (float*)p;        p += 33554432;
  float* P1 = (float*)p;        p += 33554432;
  f16* At = (f16*)p;            p += (size_t)nm * 16777216;
  f16* Bt = (f16*)p;

  float* u = out_a;             // [8192][1024]: row i = u1[i][0:512] | u2[i][512:1024]

  k_prep_x<<<dim3(8, 16, 8), 256, 0, stream>>>(inputs, Xh, XhT);
  k_prep_w<<<dim3(512, 2), 256, 0, stream>>>(W1, W2, Wh);
  k_prep_b<<<4, 256, 0, stream>>>(b1, b2, biasCat);
  // u = Xh @ WhCat^T + biasCat : 128x256 tiles, grid 256 blocks
  k_gemmG<0, 0, 512, 2, 4, 4, 4><<<dim3(4, 64, 1), 512, 0, stream>>>(
      Xh, Wh, u, biasCat, 512, 512, 0, 0);

  const int chunks = 8 / nm;
  for (int cch = 0; cch < chunks; ++cch) {
    const int m0 = cch * nm + 1;
    switch (nm) {
      case 8: k_trig<8><<<8192, 256, 0, stream>>>(u, q, At, Bt, qa, qb, m0, cch == 0); break;
      case 4: k_trig<4><<<8192, 256, 0, stream>>>(u, q, At, Bt, qa, qb, m0, cch == 0); break;
      case 2: k_trig<2><<<8192, 256, 0, stream>>>(u, q, At, Bt, qa, qb, m0, cch == 0); break;
      default: k_trig<1><<<8192, 256, 0, stream>>>(u, q, At, Bt, qa, qb, m0, cch == 0); break;
    }
    // scores partial: 128x128 tiles, BK=32, 32KB LDS -> 4 blocks/CU; K halved into z>>3
    const int Kloop = nm * 512;
    const int ldAB = nm * 1024;
    const long halfA = (long)nm * 512;
    if (cch == 0)
      k_gemm32<0><<<dim3(8, 8, 16), 256, 0, stream>>>(At, Bt, P0, Kloop, ldAB, halfA, 8388608L);
    else
      k_gemm32<1><<<dim3(8, 8, 16), 256, 0, stream>>>(At, Bt, P0, Kloop, ldAB, halfA, 8388608L);
  }

  k_softmax2<<<8192, 256, 0, stream>>>(P0, P1, qa, qb, out_a, a16);
  // h = a16 @ XhT^T : 128x128 tiles, 2 blocks/CU, grid 256 blocks
  k_gemmG<2, 0, 256, 2, 2, 4, 4><<<dim3(4, 8, 8), 256, 0, stream>>>(
      a16, XhT, out_h, nullptr, 1024, 1024, 0, 0);
}

// Round 11
// 295.150 us; speedup vs baseline: 1.4215x; 1.4215x over previous
//
#include <hip/hip_runtime.h>

typedef _Float16 f16;
typedef _Float16 f16x2 __attribute__((ext_vector_type(2)));
typedef _Float16 f16x4 __attribute__((ext_vector_type(4)));
typedef _Float16 f16x8 __attribute__((ext_vector_type(8)));
typedef float f32x4 __attribute__((ext_vector_type(4)));

#define LOG2E_X2 2.8853900817779268f

// Fourier coefficients: d_m = (2*pi/10)/sinh(pi^2*m/10); tanh(s) ~= 0.2*s + sum d_m sin(0.628319*m*s)
__constant__ float D8[8] = {0.543915f, 0.177997f, 0.0652351f, 0.0242575f,
                            0.00903807f, 0.00336823f, 0.00125536f, 0.000467884f};

static __device__ __forceinline__ void gl2lds16(const void* g, void* l) {
  __builtin_amdgcn_global_load_lds((const __attribute__((address_space(1))) void*)g,
                                   (__attribute__((address_space(3))) void*)l, 16, 0, 0);
}

// ================= new pipeline =================

// X f32 [8,1024,512] -> Xh f16 (same layout) + XhT f16 [8,512,1024]
__global__ __launch_bounds__(256) void k_prep_x(const float* __restrict__ X,
                                                f16* __restrict__ Xh, f16* __restrict__ XhT) {
  const int ht = blockIdx.x, it = blockIdx.y, b = blockIdx.z;
  __shared__ f16 Lt[64][72];
  const int t = threadIdx.x;
  const int r = t >> 4, c4 = (t & 15) * 4;
  const float* Xb = X + ((size_t)b * 1024 + it * 64) * 512 + ht * 64;
#pragma unroll
  for (int k = 0; k < 4; ++k) {
    const int rr = r + 16 * k;
    float4 v = *(const float4*)&Xb[(size_t)rr * 512 + c4];
    f16 h0 = (f16)v.x, h1 = (f16)v.y, h2 = (f16)v.z, h3 = (f16)v.w;
    *(f16x4*)&Xh[((size_t)b * 1024 + it * 64 + rr) * 512 + ht * 64 + c4] = {h0, h1, h2, h3};
    Lt[c4 + 0][rr] = h0; Lt[c4 + 1][rr] = h1; Lt[c4 + 2][rr] = h2; Lt[c4 + 3][rr] = h3;
  }
  __syncthreads();
  const int hr = t >> 2, seg = t & 3;
  f16* dst = &XhT[((size_t)b * 512 + ht * 64 + hr) * 1024 + it * 64 + seg * 16];
  *(f16x8*)(dst) = *(const f16x8*)&Lt[hr][seg * 16];
  *(f16x8*)(dst + 8) = *(const f16x8*)&Lt[hr][seg * 16 + 8];
}

// Wh = concat(W1,W2) as f16 [1024][512]
__global__ __launch_bounds__(256) void k_prep_w(const float* __restrict__ W1,
                                                const float* __restrict__ W2,
                                                f16* __restrict__ Wh) {
  const int row = blockIdx.x, z = blockIdx.y, t = threadIdx.x;
  const float* W = z ? W2 : W1;
  float2 v = *(const float2*)&W[(size_t)row * 512 + t * 2];
  *(f16x2*)&Wh[(size_t)z * 262144 + (size_t)row * 512 + t * 2] = {(f16)v.x, (f16)v.y};
}

__global__ void k_prep_b(const float* __restrict__ b1, const float* __restrict__ b2,
                         float* __restrict__ biasCat) {
  const int t = blockIdx.x * 256 + threadIdx.x;  // 1024 total
  biasCat[t] = t < 512 ? b1[t] : b2[t - 512];
}

// trig factor build; u is [8192][1024] f32, row i holds u1[i][0:512] | u2[i][512:1024]
template <int NM>
__global__ __launch_bounds__(256) void k_trig(const float* __restrict__ u,
                                              const float* __restrict__ q,
                                              f16* __restrict__ At, f16* __restrict__ Bt,
                                              float* __restrict__ qa, float* __restrict__ qb,
                                              int m0, int wq) {
  const int i = blockIdx.x, t = threadIdx.x;
  const float w = 0.62831853f;
  const float2 a2 = *(const float2*)&u[(size_t)i * 1024 + 2 * t];
  const float2 b2 = *(const float2*)&u[(size_t)i * 1024 + 512 + 2 * t];
  const float2 q2 = *(const float2*)&q[2 * t];
  if (wq) {
    float sa = q2.x * a2.x + q2.y * a2.y;
    float sb = q2.x * b2.x + q2.y * b2.y;
#pragma unroll
    for (int o = 1; o < 64; o <<= 1) { sa += __shfl_xor(sa, o); sb += __shfl_xor(sb, o); }
    __shared__ float red[8];
    const int lane = t & 63, widx = t >> 6;
    if (lane == 0) { red[widx] = sa; red[4 + widx] = sb; }
    __syncthreads();
    if (t == 0) qa[i] = red[0] + red[1] + red[2] + red[3];
    if (t == 1) qb[i] = red[4] + red[5] + red[6] + red[7];
  }
  float s1[4], c1[4], sm_[4], cm_[4];
  const float ang[4] = {w * a2.x, w * a2.y, w * b2.x, w * b2.y};
#pragma unroll
  for (int uu = 0; uu < 4; ++uu) {
    __sincosf(ang[uu], &s1[uu], &c1[uu]);
    if (m0 == 1) { sm_[uu] = s1[uu]; cm_[uu] = c1[uu]; }
    else __sincosf(m0 * ang[uu], &sm_[uu], &cm_[uu]);
  }
  const size_t ldT = (size_t)NM * 1024;
  f16* Ar = At + (size_t)i * ldT + 2 * t;
  f16* Br = Bt + (size_t)i * ldT + 2 * t;
#pragma unroll
  for (int j = 0; j < NM; ++j) {
    const float dm = D8[m0 - 1 + j];
    const float qdx = q2.x * dm, qdy = q2.y * dm;
    *(f16x2*)(Ar + j * 1024)       = {(f16)(qdx * sm_[0]), (f16)(qdy * sm_[1])};
    *(f16x2*)(Ar + j * 1024 + 512) = {(f16)(qdx * cm_[0]), (f16)(qdy * cm_[1])};
    *(f16x2*)(Br + j * 1024)       = {(f16)cm_[2], (f16)cm_[3]};
    *(f16x2*)(Br + j * 1024 + 512) = {(f16)sm_[2], (f16)sm_[3]};
    if (j + 1 < NM) {
#pragma unroll
      for (int uu = 0; uu < 4; ++uu) {
        const float ns = sm_[uu] * c1[uu] + cm_[uu] * s1[uu];
        const float nc = cm_[uu] * c1[uu] - sm_[uu] * s1[uu];
        sm_[uu] = ns; cm_[uu] = nc;
      }
    }
  }
}

// ---------- generic f16 NT GEMM, round-3 schedule (frozen), tile-parameterized ----------
// BM = WR*FI*16, BN = WC*FJ*16, BK=64, T threads (T/64 waves, WR x WC).
// MODE 0: u = Xh @ WhCat^T + biasCat       (C f32 [8192][1024])
// MODE 1: scores partials (XCD-decoded 1-D grid, K split by z-halves into P0/P1)
// MODE 2: h = a16 @ XhT^T per batch        (C f32 [8,1024,512])
template <int MODE, int ACC, int T, int WR, int WC, int FI, int FJ>
__global__ __launch_bounds__(T, 2) void k_gemmG(
    const f16* __restrict__ A, const f16* __restrict__ B, float* __restrict__ C,
    const float* __restrict__ bias0, int Kloop, int ldAB, long halfA, long halfC) {
  constexpr int BM = WR * FI * 16;
  constexpr int BN = WC * FJ * 16;
  __shared__ alignas(16) char smA[2][BM * 128];
  __shared__ alignas(16) char smB[2][BN * 128];
  const int t = threadIdx.x;
  int nx, my, z;
  if (MODE == 1) {
    // same-(my,z) blocks share lin%8 -> same XCD L2 for the A-panel
    const int lin = blockIdx.x;
    const int xcd = lin & 7, s = lin >> 3;
    const int g = xcd + 8 * (s >> 2);
    nx = s & 3; my = g & 3; z = g >> 2;
  } else {
    nx = blockIdx.x; my = blockIdx.y; z = blockIdx.z;
  }
  const f16* Ab; const f16* Bb; float* Cb; const float* bias = nullptr;
  int ldC;
  if (MODE == 0) {
    Ab = A + (size_t)my * BM * ldAB;
    Bb = B + (size_t)nx * BN * ldAB;
    Cb = C + (size_t)my * BM * 1024 + nx * BN;
    bias = bias0 + nx * BN;
    ldC = 1024;
  } else if (MODE == 1) {
    const int b = z & 7, h = z >> 3;
    Ab = A + ((size_t)(b * 1024 + my * 256)) * ldAB + h * halfA;
    Bb = B + ((size_t)(b * 1024 + nx * 256)) * ldAB + h * halfA;
    Cb = C + h * halfC + ((size_t)(b * 1024 + my * 256)) * 1024 + nx * 256;
    ldC = 1024;
  } else {
    Ab = A + (size_t)z * 1048576 + (size_t)my * BM * ldAB;
    Bb = B + (size_t)z * 524288 + (size_t)nx * BN * ldAB;
    Cb = C + (size_t)z * 524288 + (size_t)my * BM * 512 + nx * BN;
    ldC = 512;
  }
  const int wid = t >> 6, lane = t & 63;
  const int wr = wid / WC, wc = wid % WC;
  const int rl = lane & 15, kc = lane >> 4;
  f32x4 acc[FI][FJ] = {};

  auto stage = [&](int buf, int kt) {
    const f16* gA = Ab + kt * 64;
    const f16* gB = Bb + kt * 64;
    constexpr int LA = BM * 8 / T, LB = BN * 8 / T;
#pragma unroll
    for (int ii = 0; ii < LA; ++ii) {
      const int idx = ii * T + t;
      const int row = idx >> 3, c = idx & 7;
      gl2lds16(gA + (size_t)row * ldAB + ((c ^ (row & 7)) * 8),
               smA[buf] + ii * (T * 16) + wid * 1024);
    }
#pragma unroll
    for (int ii = 0; ii < LB; ++ii) {
      const int idx = ii * T + t;
      const int row = idx >> 3, c = idx & 7;
      gl2lds16(gB + (size_t)row * ldAB + ((c ^ (row & 7)) * 8),
               smB[buf] + ii * (T * 16) + wid * 1024);
    }
  };

  const int nkt = Kloop >> 6;
  stage(0, 0);
  __syncthreads();
  for (int kt = 0; kt < nkt; ++kt) {
    const int cur = kt & 1;
    if (kt + 1 < nkt) stage(cur ^ 1, kt + 1);
    const char* lA = smA[cur];
    const char* lB = smB[cur];
#pragma unroll
    for (int kk = 0; kk < 2; ++kk) {
      f16x8 av[FI], bv[FJ];
#pragma unroll
      for (int fi = 0; fi < FI; ++fi) {
        const int rloc = (wr * FI + fi) * 16 + rl;
        av[fi] = *(const f16x8*)(lA + rloc * 128 + (((kc + 4 * kk) ^ (rloc & 7)) << 4));
      }
#pragma unroll
      for (int fj = 0; fj < FJ; ++fj) {
        const int cloc = (wc * FJ + fj) * 16 + rl;
        bv[fj] = *(const f16x8*)(lB + cloc * 128 + (((kc + 4 * kk) ^ (cloc & 7)) << 4));
      }
#pragma unroll
      for (int fi = 0; fi < FI; ++fi)
#pragma unroll
        for (int fj = 0; fj < FJ; ++fj)
          acc[fi][fj] = __builtin_amdgcn_mfma_f32_16x16x32_f16(av[fi], bv[fj], acc[fi][fj], 0, 0, 0);
    }
    __syncthreads();
  }

#pragma unroll
  for (int fj = 0; fj < FJ; ++fj) {
    const int gcol = (wc * FJ + fj) * 16 + rl;
    const float bvv = (MODE == 0) ? bias[gcol] : 0.f;
#pragma unroll
    for (int fi = 0; fi < FI; ++fi) {
      const int grow0 = (wr * FI + fi) * 16 + kc * 4;
      f32x4 v = acc[fi][fj];
#pragma unroll
      for (int r = 0; r < 4; ++r) {
        const size_t o = (size_t)(grow0 + r) * ldC + gcol;
        float x = v[r] + bvv;
        if (ACC) x += Cb[o];
        Cb[o] = x;
      }
    }
  }
}

// softmax over j of u = P0+P1+0.2*(qa_i+qb_j); writes a (f32) and a16 (f16)
__global__ __launch_bounds__(256) void k_softmax2(const float* __restrict__ P0,
                                                  const float* __restrict__ P1,
                                                  const float* __restrict__ qa,
                                                  const float* __restrict__ qb,
                                                  float* __restrict__ out_a,
                                                  f16* __restrict__ a16) {
  const int row = blockIdx.x, t = threadIdx.x;
  const int b = row >> 10;
  const size_t off = (size_t)row * 1024 + t * 4;
  float4 p0 = *(const float4*)(P0 + off);
  float4 p1 = *(const float4*)(P1 + off);
  float4 qb4 = *(const float4*)(qb + (size_t)b * 1024 + t * 4);
  const float qi = qa[row];
  float4 v;
  v.x = p0.x + p1.x + 0.2f * (qi + qb4.x);
  v.y = p0.y + p1.y + 0.2f * (qi + qb4.y);
  v.z = p0.z + p1.z + 0.2f * (qi + qb4.z);
  v.w = p0.w + p1.w + 0.2f * (qi + qb4.w);
  float m = fmaxf(fmaxf(v.x, v.y), fmaxf(v.z, v.w));
#pragma unroll
  for (int o = 1; o < 64; o <<= 1) m = fmaxf(m, __shfl_xor(m, o));
  __shared__ float red[4];
  const int w = t >> 6, ln = t & 63;
  if (ln == 0) red[w] = m;
  __syncthreads();
  m = fmaxf(fmaxf(red[0], red[1]), fmaxf(red[2], red[3]));
  v.x = __expf(v.x - m); v.y = __expf(v.y - m);
  v.z = __expf(v.z - m); v.w = __expf(v.w - m);
  float s = v.x + v.y + v.z + v.w;
#pragma unroll
  for (int o = 1; o < 64; o <<= 1) s += __shfl_xor(s, o);
  __syncthreads();
  if (ln == 0) red[w] = s;
  __syncthreads();
  s = red[0] + red[1] + red[2] + red[3];
  const float inv = 1.0f / s;
  v.x *= inv; v.y *= inv; v.z *= inv; v.w *= inv;
  *(float4*)(out_a + off) = v;
  *(f16x4*)(a16 + off) = {(f16)v.x, (f16)v.y, (f16)v.z, (f16)v.w};
}

// ================= old (fallback) pipeline =================
typedef short s16x2 __attribute__((ext_vector_type(2)));

static __device__ __forceinline__ float fdot2f(f16x2 a, f16x2 b, float c) {
#if __has_builtin(__builtin_amdgcn_fdot2)
  return __builtin_amdgcn_fdot2(a, b, c, false);
#else
  return c + (float)a[0] * (float)b[0] + (float)a[1] * (float)b[1];
#endif
}

__global__ void k_qprep(const float* __restrict__ q, f16* __restrict__ qh,
                        float* __restrict__ qsum) {
  const int t = threadIdx.x;
  float v = q[t];
  qh[t] = (f16)v;
  float s = v;
#pragma unroll
  for (int o = 1; o < 64; o <<= 1) s += __shfl_xor(s, o);
  __shared__ float red[8];
  if ((t & 63) == 0) red[t >> 6] = s;
  __syncthreads();
  if (t == 0) {
    float tot = 0.f;
#pragma unroll
    for (int i = 0; i < 8; ++i) tot += red[i];
    *qsum = tot;
  }
}

__global__ __launch_bounds__(256) void k_gemm_exp(
    const float* __restrict__ X, const float* __restrict__ W1,
    const float* __restrict__ b1, const float* __restrict__ W2,
    const float* __restrict__ b2, f16* __restrict__ e1, f16* __restrict__ e2) {
  const int z = blockIdx.z;
  const float* W = z ? W2 : W1;
  const float* bias = z ? b2 : b1;
  f16* out = z ? e2 : e1;
  const int r0 = blockIdx.y * 64;
  const int c0 = blockIdx.x * 64;
  __shared__ alignas(16) float Xs[64][68];
  __shared__ alignas(16) float Ws[64][68];
  const int t = threadIdx.x;
  const int row = t >> 2, seg = t & 3;
  const int tr = t >> 4, tc = t & 15;
  float acc[4][4] = {};
#pragma unroll 1
  for (int k0 = 0; k0 < 512; k0 += 64) {
    const float4* gx = (const float4*)(X + (size_t)(r0 + row) * 512 + k0 + seg * 16);
    float4* lx = (float4*)(&Xs[row][seg * 16]);
    lx[0] = gx[0]; lx[1] = gx[1]; lx[2] = gx[2]; lx[3] = gx[3];
    const float4* gw = (const float4*)(W + (size_t)(c0 + row) * 512 + k0 + seg * 16);
    float4* lw = (float4*)(&Ws[row][seg * 16]);
    lw[0] = gw[0]; lw[1] = gw[1]; lw[2] = gw[2]; lw[3] = gw[3];
    __syncthreads();
#pragma unroll 4
    for (int kk = 0; kk < 64; kk += 4) {
      float4 av[4], bv[4];
#pragma unroll
      for (int ii = 0; ii < 4; ++ii) av[ii] = *(const float4*)&Xs[tr + 16 * ii][kk];
#pragma unroll
      for (int jj = 0; jj < 4; ++jj) bv[jj] = *(const float4*)&Ws[tc + 16 * jj][kk];
#pragma unroll
      for (int ii = 0; ii < 4; ++ii) {
#pragma unroll
        for (int jj = 0; jj < 4; ++jj) {
          acc[ii][jj] = fmaf(av[ii].x, bv[jj].x, acc[ii][jj]);
          acc[ii][jj] = fmaf(av[ii].y, bv[jj].y, acc[ii][jj]);
          acc[ii][jj] = fmaf(av[ii].z, bv[jj].z, acc[ii][jj]);
          acc[ii][jj] = fmaf(av[ii].w, bv[jj].w, acc[ii][jj]);
        }
      }
    }
    __syncthreads();
  }
#pragma unroll
  for (int ii = 0; ii < 4; ++ii) {
    const int r = r0 + tr + 16 * ii;
#pragma unroll
    for (int jj = 0; jj < 4; ++jj) {
      const int c = c0 + tc + 16 * jj;
      float u = acc[ii][jj] + bias[c];
      float val = u * LOG2E_X2 - 4.0f;
      val = fminf(6.6759f, fmaxf(-14.6759f, val));
      out[(size_t)r * 512 + c] = (f16)exp2f(val);
    }
  }
}

template <int P>
static __device__ __forceinline__ void tanh_dot_step(const f16x8 (&Av)[4],
                                                     const f16x8 (&Bv)[4],
                                                     const f16x8& Qv, float (&acc)[4][4],
                                                     int c256, int kmag, int two2) {
  f16x2 qp = __builtin_shufflevector(Qv, Qv, 2 * P, 2 * P + 1);
#pragma unroll
  for (int jj = 0; jj < 4; ++jj) {
    f16x2 bp = __builtin_shufflevector(Bv[jj], Bv[jj], 2 * P, 2 * P + 1);
#pragma unroll
    for (int ii = 0; ii < 4; ++ii) {
      f16x2 ap = __builtin_shufflevector(Av[ii], Av[ii], 2 * P, 2 * P + 1);
      f16x2 d, r, tt;
      asm("v_pk_fma_f16 %0, %3, %4, %5\n\t"
          "v_pk_sub_i16 %1, %6, %0\n\t"
          "v_pk_fma_f16 %2, %0, %1, %7 neg_lo:[1,0,0] neg_hi:[1,0,0]\n\t"
          "v_pk_mul_f16 %1, %1, %2\n\t"
          "v_pk_fma_f16 %2, %0, %1, %7 neg_lo:[1,0,0] neg_hi:[1,0,0]\n\t"
          "v_pk_mul_f16 %1, %1, %2"
          : "=&v"(d), "=&v"(r), "=&v"(tt)
          : "v"(ap), "v"(bp), "v"(c256), "v"(kmag), "v"(two2));
      acc[ii][jj] = fdot2f(r, qp, acc[ii][jj]);
    }
  }
}

__global__ __launch_bounds__(256) void k_scores(const f16* __restrict__ e1,
                                                const f16* __restrict__ e2,
                                                const f16* __restrict__ qh,
                                                const float* __restrict__ qsum_p,
                                                float* __restrict__ out_a) {
  const int b = blockIdx.z, it = blockIdx.y, jt = blockIdx.x;
  __shared__ alignas(16) f16 As[64][72];
  __shared__ alignas(16) f16 Bs[64][72];
  __shared__ alignas(16) f16 Qs[512];
  const int t = threadIdx.x;
  const size_t eA = (size_t)(b * 1024 + it * 64) * 512;
  const size_t eB = (size_t)(b * 1024 + jt * 64) * 512;
  if (t < 64) ((uint4*)Qs)[t] = ((const uint4*)qh)[t];
  const int row = t >> 2, seg = t & 3;
  const int tr = t >> 4, tc = t & 15;
  const int c256 = 0x1C001C00;
  const int kmag = 0x77987798;
  const int two2 = 0x40004000;
  float acc[4][4] = {};
#pragma unroll 1
  for (int h0 = 0; h0 < 512; h0 += 64) {
    const f16* gA = e1 + eA + (size_t)row * 512 + h0;
    const f16* gB = e2 + eB + (size_t)row * 512 + h0;
    *(uint4*)(&As[row][seg * 8]) = *(const uint4*)(gA + seg * 8);
    *(uint4*)(&As[row][seg * 8 + 32]) = *(const uint4*)(gA + seg * 8 + 32);
    *(uint4*)(&Bs[row][seg * 8]) = *(const uint4*)(gB + seg * 8);
    *(uint4*)(&Bs[row][seg * 8 + 32]) = *(const uint4*)(gB + seg * 8 + 32);
    __syncthreads();
#pragma unroll 2
    for (int g = 0; g < 8; ++g) {
      f16x8 Av[4], Bv[4], Qv;
#pragma unroll
      for (int ii = 0; ii < 4; ++ii) Av[ii] = *(const f16x8*)&As[tr + 16 * ii][g * 8];
#pragma unroll
      for (int jj = 0; jj < 4; ++jj) Bv[jj] = *(const f16x8*)&Bs[tc + 16 * jj][g * 8];
      Qv = *(const f16x8*)&Qs[h0 + g * 8];
      tanh_dot_step<0>(Av, Bv, Qv, acc, c256, kmag, two2);
      tanh_dot_step<1>(Av, Bv, Qv, acc, c256, kmag, two2);
      tanh_dot_step<2>(Av, Bv, Qv, acc, c256, kmag, two2);
      tanh_dot_step<3>(Av, Bv, Qv, acc, c256, kmag, two2);
    }
    __syncthreads();
  }
  const float qs = *qsum_p;
#pragma unroll
  for (int ii = 0; ii < 4; ++ii) {
    const size_t orow = (size_t)(b * 1024 + it * 64 + tr + 16 * ii) * 1024;
#pragma unroll
    for (int jj = 0; jj < 4; ++jj)
      out_a[orow + jt * 64 + tc + 16 * jj] = qs - acc[ii][jj] * (1.0f / 128.0f);
  }
}

__global__ __launch_bounds__(256) void k_softmax(float* __restrict__ a) {
  float* row = a + (size_t)blockIdx.x * 1024;
  const int t = threadIdx.x;
  float4 v = ((const float4*)row)[t];
  float m = fmaxf(fmaxf(v.x, v.y), fmaxf(v.z, v.w));
#pragma unroll
  for (int o = 1; o < 64; o <<= 1) m = fmaxf(m, __shfl_xor(m, o));
  __shared__ float red[4];
  const int w = t >> 6, ln = t & 63;
  if (ln == 0) red[w] = m;
  __syncthreads();
  m = fmaxf(fmaxf(red[0], red[1]), fmaxf(red[2], red[3]));
  v.x = __expf(v.x - m); v.y = __expf(v.y - m);
  v.z = __expf(v.z - m); v.w = __expf(v.w - m);
  float s = v.x + v.y + v.z + v.w;
#pragma unroll
  for (int o = 1; o < 64; o <<= 1) s += __shfl_xor(s, o);
  __syncthreads();
  if (ln == 0) red[w] = s;
  __syncthreads();
  s = red[0] + red[1] + red[2] + red[3];
  const float inv = 1.0f / s;
  v.x *= inv; v.y *= inv; v.z *= inv; v.w *= inv;
  ((float4*)row)[t] = v;
}

__global__ __launch_bounds__(256) void k_av(const float* __restrict__ a,
                                            const float* __restrict__ X,
                                            float* __restrict__ h) {
  const int b = blockIdx.z;
  const int i0 = blockIdx.y * 64;
  const int c0 = blockIdx.x * 64;
  __shared__ alignas(16) float As[64][68];
  __shared__ alignas(16) float Xs[64][68];
  const float* Ab = a + (size_t)b * 1024 * 1024;
  const float* Xb = X + (size_t)b * 1024 * 512;
  const int t = threadIdx.x;
  const int row = t >> 2, seg = t & 3;
  const int tr = t >> 4, tc = t & 15;
  float acc[4][4] = {};
#pragma unroll 1
  for (int k0 = 0; k0 < 1024; k0 += 64) {
    const float4* ga = (const float4*)(Ab + (size_t)(i0 + row) * 1024 + k0 + seg * 16);
    float4* la = (float4*)(&As[row][seg * 16]);
    la[0] = ga[0]; la[1] = ga[1]; la[2] = ga[2]; la[3] = ga[3];
    const float4* gx = (const float4*)(Xb + (size_t)(k0 + row) * 512 + c0 + seg * 16);
    float4* lx = (float4*)(&Xs[row][seg * 16]);
    lx[0] = gx[0]; lx[1] = gx[1]; lx[2] = gx[2]; lx[3] = gx[3];
    __syncthreads();
#pragma unroll 8
    for (int k = 0; k < 64; ++k) {
      float av[4], bv[4];
#pragma unroll
      for (int ii = 0; ii < 4; ++ii) av[ii] = As[tr + 16 * ii][k];
#pragma unroll
      for (int jj = 0; jj < 4; ++jj) bv[jj] = Xs[k][tc + 16 * jj];
#pragma unroll
      for (int ii = 0; ii < 4; ++ii) {
#pragma unroll
        for (int jj = 0; jj < 4; ++jj)
          acc[ii][jj] = fmaf(av[ii], bv[jj], acc[ii][jj]);
      }
    }
    __syncthreads();
  }
#pragma unroll
  for (int ii = 0; ii < 4; ++ii) {
    const size_t orow = (size_t)b * 1024 * 512 + (size_t)(i0 + tr + 16 * ii) * 512;
#pragma unroll
    for (int jj = 0; jj < 4; ++jj)
      h[orow + c0 + tc + 16 * jj] = acc[ii][jj];
  }
}

// ================= host =================
extern "C" void kernel_launch(void* const* d_in, const int* in_sizes, int n_in,
                              void* d_out, int out_size, void* d_ws, size_t ws_size,
                              hipStream_t stream) {
  const float* inputs = (const float*)d_in[0];
  const float* W1 = (const float*)d_in[1];
  const float* b1 = (const float*)d_in[2];
  const float* W2 = (const float*)d_in[3];
  const float* b2 = (const float*)d_in[4];
  const float* q = (const float*)d_in[5];

  float* out_h = (float*)d_out;            // [8,1024,512]
  float* out_a = out_h + 4194304;          // [8,1024,1024]

  const size_t FIXED = 101781504ULL;       // Xh+XhT+Wh+a16+qa+qb+biasCat+P0+P1
  const size_t PER_M = 33554432ULL;        // A+B trig per m
  if (ws_size < FIXED + PER_M) {
    // fallback: verified elementwise pipeline (needs only ~17 MB)
    char* ws = (char*)d_ws;
    f16* e1 = (f16*)ws;
    f16* e2 = (f16*)(ws + 8388608);
    f16* qh = (f16*)(ws + 16777216);
    float* qsum = (float*)(ws + 16778240);
    k_qprep<<<1, 512, 0, stream>>>(q, qh, qsum);
    k_gemm_exp<<<dim3(8, 128, 2), 256, 0, stream>>>(inputs, W1, b1, W2, b2, e1, e2);
    k_scores<<<dim3(16, 16, 8), 256, 0, stream>>>(e1, e2, qh, qsum, out_a);
    k_softmax<<<8192, 256, 0, stream>>>(out_a);
    k_av<<<dim3(8, 16, 8), 256, 0, stream>>>(out_a, inputs, out_h);
    return;
  }

  int nm = 8;
  while (FIXED + (size_t)nm * PER_M > ws_size) nm >>= 1;

  char* p = (char*)d_ws;
  f16* Xh = (f16*)p;            p += 8388608;
  f16* XhT = (f16*)p;           p += 8388608;
  f16* Wh = (f16*)p;            p += 1048576;
  f16* a16 = (f16*)p;           p += 16777216;
  float* qa = (float*)p;        p += 32768;
  float* qb = (float*)p;        p += 32768;
  float* biasCat = (float*)p;   p += 4096;
  float* P0 = (float*)p;        p += 33554432;
  float* P1 = (float*)p;        p += 33554432;
  f16* At = (f16*)p;            p += (size_t)nm * 16777216;
  f16* Bt = (f16*)p;

  float* u = out_a;             // [8192][1024]: row i = u1[i][0:512] | u2[i][512:1024]

  k_prep_x<<<dim3(8, 16, 8), 256, 0, stream>>>(inputs, Xh, XhT);
  k_prep_w<<<dim3(512, 2), 256, 0, stream>>>(W1, W2, Wh);
  k_prep_b<<<4, 256, 0, stream>>>(b1, b2, biasCat);
  // u = Xh @ WhCat^T + biasCat : 128x256 tiles, grid 256 blocks
  k_gemmG<0, 0, 512, 2, 4, 4, 4><<<dim3(4, 64, 1), 512, 0, stream>>>(
      Xh, Wh, u, biasCat, 512, 512, 0, 0);

  const int chunks = 8 / nm;
  for (int cch = 0; cch < chunks; ++cch) {
    const int m0 = cch * nm + 1;
    switch (nm) {
      case 8: k_trig<8><<<8192, 256, 0, stream>>>(u, q, At, Bt, qa, qb, m0, cch == 0); break;
      case 4: k_trig<4><<<8192, 256, 0, stream>>>(u, q, At, Bt, qa, qb, m0, cch == 0); break;
      case 2: k_trig<2><<<8192, 256, 0, stream>>>(u, q, At, Bt, qa, qb, m0, cch == 0); break;
      default: k_trig<1><<<8192, 256, 0, stream>>>(u, q, At, Bt, qa, qb, m0, cch == 0); break;
    }
    const int Kloop = nm * 512;       // each z-half covers half the chunk's K
    const int ldAB = nm * 1024;
    const long halfA = (long)nm * 512;
    if (cch == 0)
      k_gemmG<1, 0, 512, 2, 4, 8, 4><<<dim3(256, 1, 1), 512, 0, stream>>>(
          At, Bt, P0, nullptr, Kloop, ldAB, halfA, 8388608L);
    else
      k_gemmG<1, 1, 512, 2, 4, 8, 4><<<dim3(256, 1, 1), 512, 0, stream>>>(
          At, Bt, P0, nullptr, Kloop, ldAB, halfA, 8388608L);
  }

  k_softmax2<<<8192, 256, 0, stream>>>(P0, P1, qa, qb, out_a, a16);
  // h = a16 @ XhT^T : 128x128 tiles, 2 blocks/CU, grid 256 blocks
  k_gemmG<2, 0, 256, 2, 2, 4, 4><<<dim3(4, 8, 8), 256, 0, stream>>>(
      a16, XhT, out_h, nullptr, 1024, 1024, 0, 0);
}